// Round 5
// baseline (140.587 us; speedup 1.0000x reference)
//
#include <hip/hip_runtime.h>

// Elman RNN via split-bf16 MFMA, 2 tiles/wave.  B=262144, T=10, I=1, H=32.
// out = [outs (B*T floats)] ++ [h_last (B*H floats)]
//
// R4 diagnosis: 55us, MfmaUtil 15%, VALUBusy 60%, HBM 15% -> latency-bound
// single dependency chain per wave. This round:
//  - B-fragment rebuild via v_permlane32_swap_b32 (8 swaps replace
//    8 ds_bpermute + ~40 cndmask; removes lgkm wait from the chain)
//  - drop the lo*lo split terms (8 -> 6 MFMAs, error ~2^-18)
//  - 2 independent 32-batch tiles per wave (2 chains -> ILP x2)
//  - rolled t-loop with 1-step x prefetch (no runtime-indexed reg arrays)
//
// Layouts (C/D guide-verified for 32x32x16 bf16; A/B verified by R4 pass):
//   C/D: col = lane&31, row = (reg&3) + 8*(reg>>2) + 4*(lane>>5)
//   A:   lane holds A[row=lane&31][k = (lane>>5)*8 + j], j=0..7
//   B:   lane holds B[k = (lane>>5)*8 + j][col=lane&31]
// permlane32_swap(X,Y): X'[i]=X[i], X'[32+i]=Y[i]; Y'[i]=X[32+i], Y'[32+i]=Y[32+i]
//   swap(S0,S2) -> {B1 reg0, B1 reg2}; swap(S1,S3) -> {B1 reg1, B1 reg3};
//   swap(S4,S6) -> {B2 reg0, B2 reg2}; swap(S5,S7) -> {B2 reg1, B2 reg3}.

#define RNN_T 10
#define RNN_H 32

typedef __attribute__((ext_vector_type(4))) unsigned int u32x4;
typedef __attribute__((ext_vector_type(8))) short s16x8;
typedef __attribute__((ext_vector_type(16))) float f32x16;

static __device__ __forceinline__ float fast_tanh(float a) {
    // tanh(a) = 1 - 2/(exp(2a)+1); saturates correctly at +-inf.
    float ez = __builtin_amdgcn_exp2f(a * 2.885390081777927f);
    float r  = __builtin_amdgcn_rcpf(ez + 1.0f);
    return fmaf(-2.0f, r, 1.0f);
}

// pack bf16-trunc(f0) [low 16] and bf16-trunc(f1) [high 16] into one u32
static __device__ __forceinline__ unsigned pack_hi_pair(float f0, float f1) {
    return (__float_as_uint(f1) & 0xffff0000u) | (__float_as_uint(f0) >> 16);
}
static __device__ __forceinline__ float trunc_bf16_f32(float f) {
    return __uint_as_float(__float_as_uint(f) & 0xffff0000u);
}

static __device__ __forceinline__ f32x16 mfma_bf16(u32x4 a, u32x4 b, f32x16 c) {
    return __builtin_amdgcn_mfma_f32_32x32x16_bf16(
        __builtin_bit_cast(s16x8, a), __builtin_bit_cast(s16x8, b), c, 0, 0, 0);
}

// load 8 consecutive floats, split into bf16 hi fragment + bf16 residual fragment
static __device__ __forceinline__ void load_split8(const float* __restrict__ p,
                                                   u32x4& hi4, u32x4& lo4) {
    float4 w0 = *reinterpret_cast<const float4*>(p);
    float4 w1 = *reinterpret_cast<const float4*>(p + 4);
    float w[8] = {w0.x, w0.y, w0.z, w0.w, w1.x, w1.y, w1.z, w1.w};
    #pragma unroll
    for (int i = 0; i < 4; ++i) {
        float f0 = w[2 * i], f1 = w[2 * i + 1];
        hi4[i] = pack_hi_pair(f0, f1);
        lo4[i] = pack_hi_pair(f0 - trunc_bf16_f32(f0), f1 - trunc_bf16_f32(f1));
    }
}

static __device__ __forceinline__ void swap32(unsigned& xv, unsigned& yv) {
    asm volatile("v_permlane32_swap_b32 %0, %1" : "+v"(xv), "+v"(yv));
}

// S[p] = packed-bf16 pair (h[2p],h[2p+1]) in D-layout -> B-frag K-halves.
static __device__ __forceinline__ void rebuild(const unsigned S[8],
                                               u32x4& Bk1, u32x4& Bk2) {
    unsigned a, b;
    a = S[0]; b = S[2]; swap32(a, b); Bk1[0] = a; Bk1[2] = b;
    a = S[1]; b = S[3]; swap32(a, b); Bk1[1] = a; Bk1[3] = b;
    a = S[4]; b = S[6]; swap32(a, b); Bk2[0] = a; Bk2[2] = b;
    a = S[5]; b = S[7]; swap32(a, b); Bk2[1] = a; Bk2[3] = b;
}

__global__ __launch_bounds__(256) void rnn_mfma2(
    const float* __restrict__ x,     // [B,T]
    const float* __restrict__ hin,   // [B,H]
    const float* __restrict__ Wih,   // [H]
    const float* __restrict__ Whh,   // [H,H]
    const float* __restrict__ bih,   // [H]
    const float* __restrict__ bhh,   // [H]
    const float* __restrict__ Wout,  // [H]
    const float* __restrict__ bout,  // [1]
    float* __restrict__ out,         // [B*T] ++ [B*H]
    int B)
{
    const int tid  = threadIdx.x;
    const int lane = tid & 63;
    const int l31  = lane & 31;
    const int hi   = lane >> 5;
    const int wave = tid >> 6;
    const int b0   = (blockIdx.x * 8 + wave * 2) * 32 + l31;  // tile pair
    const int b1   = b0 + 32;
    const int kb   = hi * 8;

    // ---- A fragments: Whh split hi/lo, both K-halves. Loaded ONCE. ----
    u32x4 A1h, A1l, A2h, A2l;
    load_split8(Whh + l31 * RNN_H + kb,      A1h, A1l);   // k = 0..15
    load_split8(Whh + l31 * RNN_H + 16 + kb, A2h, A2l);   // k = 16..31

    // ---- initial B fragments from h0, two tiles ----
    u32x4 B1h0, B1l0, B2h0, B2l0, B1h1, B1l1, B2h1, B2l1;
    load_split8(hin + (size_t)b0 * RNN_H + kb,      B1h0, B1l0);
    load_split8(hin + (size_t)b0 * RNN_H + 16 + kb, B2h0, B2l0);
    load_split8(hin + (size_t)b1 * RNN_H + kb,      B1h1, B1l1);
    load_split8(hin + (size_t)b1 * RNN_H + 16 + kb, B2h1, B2l1);

    // ---- per-reg row constants: row(r) = (r&3) + 8*(r>>2) + 4*hi ----
    float wih_r[16], bias_r[16], wout_r[16];
    #pragma unroll
    for (int r = 0; r < 16; ++r) {
        int row = (r & 3) + 8 * (r >> 2) + 4 * hi;
        wih_r[r]  = Wih[row];
        bias_r[r] = bih[row] + bhh[row];
        wout_r[r] = Wout[row];
    }

    const float bo = bout[0];
    const float* xp0 = x + (size_t)b0 * RNN_T;
    const float* xp1 = x + (size_t)b1 * RNN_T;
    float* op0 = out + (size_t)b0 * RNN_T;
    float* op1 = out + (size_t)b1 * RNN_T;

    float h0r[16], h1r[16];
    float xc0 = xp0[0], xc1 = xp1[0];

    #pragma unroll 1   // rolled: ~500-instr body, runtime t only in addresses
    for (int t = 0; t < RNN_T; ++t) {
        const int tn = (t < RNN_T - 1) ? t + 1 : t;   // branchless prefetch idx
        const float xn0 = xp0[tn], xn1 = xp1[tn];     // hides under this body

        f32x16 acc0, acc1;
        #pragma unroll
        for (int r = 0; r < 16; ++r) {
            acc0[r] = fmaf(xc0, wih_r[r], bias_r[r]);
            acc1[r] = fmaf(xc1, wih_r[r], bias_r[r]);
        }
        // 6 MFMAs/tile (hi*hi, hi*lo, lo*hi; lo*lo dropped, ~2^-18)
        acc0 = mfma_bf16(A1h, B1h0, acc0);  acc1 = mfma_bf16(A1h, B1h1, acc1);
        acc0 = mfma_bf16(A2h, B2h0, acc0);  acc1 = mfma_bf16(A2h, B2h1, acc1);
        acc0 = mfma_bf16(A1h, B1l0, acc0);  acc1 = mfma_bf16(A1h, B1l1, acc1);
        acc0 = mfma_bf16(A2h, B2l0, acc0);  acc1 = mfma_bf16(A2h, B2l1, acc1);
        acc0 = mfma_bf16(A1l, B1h0, acc0);  acc1 = mfma_bf16(A1l, B1h1, acc1);
        acc0 = mfma_bf16(A2l, B2h0, acc0);  acc1 = mfma_bf16(A2l, B2h1, acc1);

        #pragma unroll
        for (int r = 0; r < 16; ++r) {
            h0r[r] = fast_tanh(acc0[r]);
            h1r[r] = fast_tanh(acc1[r]);
        }

        // output head: o = sum_j h[j]*Wout[j]; partner holds the other 16 rows
        float o0 = 0.f, o1 = 0.f;
        #pragma unroll
        for (int r = 0; r < 16; ++r) {
            o0 = fmaf(h0r[r], wout_r[r], o0);
            o1 = fmaf(h1r[r], wout_r[r], o1);
        }
        unsigned oa0 = __float_as_uint(o0), ob0 = oa0;
        unsigned oa1 = __float_as_uint(o1), ob1 = oa1;
        swap32(oa0, ob0);   // lo lanes: oa0 = own, ob0 = partner's
        swap32(oa1, ob1);
        if (lane < 32) {
            op0[t] = __uint_as_float(oa0) + __uint_as_float(ob0) + bo;
            op1[t] = __uint_as_float(oa1) + __uint_as_float(ob1) + bo;
        }

        // rebuild next-step B fragments (done at t=9 too: ~1% waste, no branch)
        unsigned Sh[8], Sl[8];
        #pragma unroll
        for (int p = 0; p < 8; ++p) {
            float f0 = h0r[2 * p], f1 = h0r[2 * p + 1];
            Sh[p] = pack_hi_pair(f0, f1);
            Sl[p] = pack_hi_pair(f0 - trunc_bf16_f32(f0), f1 - trunc_bf16_f32(f1));
        }
        rebuild(Sh, B1h0, B2h0);
        rebuild(Sl, B1l0, B2l0);
        #pragma unroll
        for (int p = 0; p < 8; ++p) {
            float f0 = h1r[2 * p], f1 = h1r[2 * p + 1];
            Sh[p] = pack_hi_pair(f0, f1);
            Sl[p] = pack_hi_pair(f0 - trunc_bf16_f32(f0), f1 - trunc_bf16_f32(f1));
        }
        rebuild(Sh, B1h1, B2h1);
        rebuild(Sl, B1l1, B2l1);

        xc0 = xn0; xc1 = xn1;
    }

    // ---- final hidden state: rows 8q+4*hi+0..3 are h[4q..4q+3] ----
    float* hl0 = out + (size_t)B * RNN_T + (size_t)b0 * RNN_H;
    float* hl1 = out + (size_t)B * RNN_T + (size_t)b1 * RNN_H;
    #pragma unroll
    for (int q = 0; q < 4; ++q) {
        float4 v0 = make_float4(h0r[4*q], h0r[4*q+1], h0r[4*q+2], h0r[4*q+3]);
        float4 v1 = make_float4(h1r[4*q], h1r[4*q+1], h1r[4*q+2], h1r[4*q+3]);
        *reinterpret_cast<float4*>(hl0 + 8 * q + 4 * hi) = v0;
        *reinterpret_cast<float4*>(hl1 + 8 * q + 4 * hi) = v1;
    }
}

extern "C" void kernel_launch(void* const* d_in, const int* in_sizes, int n_in,
                              void* d_out, int out_size, void* d_ws, size_t ws_size,
                              hipStream_t stream) {
    const float* x    = (const float*)d_in[0];
    const float* h0   = (const float*)d_in[1];
    const float* Wih  = (const float*)d_in[2];
    const float* Whh  = (const float*)d_in[3];
    const float* bih  = (const float*)d_in[4];
    const float* bhh  = (const float*)d_in[5];
    const float* Wout = (const float*)d_in[6];
    const float* bout = (const float*)d_in[7];
    float* out = (float*)d_out;

    const int B = in_sizes[1] / RNN_H;     // 262144
    dim3 grid(B / 256);                    // 4 waves/block x 2 tiles x 32 batches
    dim3 block(256);
    hipLaunchKernelGGL(rnn_mfma2, grid, block, 0, stream,
                       x, h0, Wih, Whh, bih, bhh, Wout, bout, out, B);
}

// Round 10
// 140.117 us; speedup vs baseline: 1.0034x; 1.0034x over previous
//
#include <hip/hip_runtime.h>

// Elman RNN via split-bf16 MFMA.  B=262144, T=10, I=1, H=32.
// out = [outs (B*T floats)] ++ [h_last (B*H floats)]
//
// R9 = R5 (last PASSING kernel, 57.6us) with tile 1 deleted — nothing else.
// R6/R7/R8 failed identically (absmax 1.0024) after bundling {full unroll,
// float2 preload, skip-t9, 1-tile}; early-clobber fix changed nothing, so
// the full-unroll x inline-asm interaction is the prime suspect. This round
// bisects: keep R5's ROLLED t-loop + per-step x + always-rebuild + exact
// "+v" swap32, only removing the second tile (pure deletion; per-batch math
// bit-identical to R5) and doubling the grid to 2048 blocks.
//
// Layouts (C/D guide-verified for 32x32x16 bf16; A/B verified by R4/R5 pass):
//   C/D: col = lane&31, row = (reg&3) + 8*(reg>>2) + 4*(lane>>5)
//   A:   lane holds A[row=lane&31][k = (lane>>5)*8 + j], j=0..7
//   B:   lane holds B[k = (lane>>5)*8 + j][col=lane&31]
// permlane32_swap(X,Y): X'[i]=X[i], X'[32+i]=Y[i]; Y'[i]=X[32+i], Y'[32+i]=Y[32+i]

#define RNN_T 10
#define RNN_H 32

typedef __attribute__((ext_vector_type(4))) unsigned int u32x4;
typedef __attribute__((ext_vector_type(8))) short s16x8;
typedef __attribute__((ext_vector_type(16))) float f32x16;

static __device__ __forceinline__ float fast_tanh(float a) {
    // tanh(a) = 1 - 2/(exp(2a)+1); saturates correctly at +-inf.
    float ez = __builtin_amdgcn_exp2f(a * 2.885390081777927f);
    float r  = __builtin_amdgcn_rcpf(ez + 1.0f);
    return fmaf(-2.0f, r, 1.0f);
}

// pack bf16-trunc(f0) [low 16] and bf16-trunc(f1) [high 16] into one u32
static __device__ __forceinline__ unsigned pack_hi_pair(float f0, float f1) {
    return (__float_as_uint(f1) & 0xffff0000u) | (__float_as_uint(f0) >> 16);
}
static __device__ __forceinline__ float trunc_bf16_f32(float f) {
    return __uint_as_float(__float_as_uint(f) & 0xffff0000u);
}

static __device__ __forceinline__ f32x16 mfma_bf16(u32x4 a, u32x4 b, f32x16 c) {
    return __builtin_amdgcn_mfma_f32_32x32x16_bf16(
        __builtin_bit_cast(s16x8, a), __builtin_bit_cast(s16x8, b), c, 0, 0, 0);
}

// load 8 consecutive floats, split into bf16 hi fragment + bf16 residual fragment
static __device__ __forceinline__ void load_split8(const float* __restrict__ p,
                                                   u32x4& hi4, u32x4& lo4) {
    float4 w0 = *reinterpret_cast<const float4*>(p);
    float4 w1 = *reinterpret_cast<const float4*>(p + 4);
    float w[8] = {w0.x, w0.y, w0.z, w0.w, w1.x, w1.y, w1.z, w1.w};
    #pragma unroll
    for (int i = 0; i < 4; ++i) {
        float f0 = w[2 * i], f1 = w[2 * i + 1];
        hi4[i] = pack_hi_pair(f0, f1);
        lo4[i] = pack_hi_pair(f0 - trunc_bf16_f32(f0), f1 - trunc_bf16_f32(f1));
    }
}

static __device__ __forceinline__ void swap32(unsigned& xv, unsigned& yv) {
    asm volatile("v_permlane32_swap_b32 %0, %1" : "+v"(xv), "+v"(yv));
}

// S[p] = packed-bf16 pair (h[2p],h[2p+1]) in D-layout -> B-frag K-halves.
static __device__ __forceinline__ void rebuild(const unsigned S[8],
                                               u32x4& Bk1, u32x4& Bk2) {
    unsigned a, b;
    a = S[0]; b = S[2]; swap32(a, b); Bk1[0] = a; Bk1[2] = b;
    a = S[1]; b = S[3]; swap32(a, b); Bk1[1] = a; Bk1[3] = b;
    a = S[4]; b = S[6]; swap32(a, b); Bk2[0] = a; Bk2[2] = b;
    a = S[5]; b = S[7]; swap32(a, b); Bk2[1] = a; Bk2[3] = b;
}

__global__ __launch_bounds__(256) void rnn_mfma5(
    const float* __restrict__ x,     // [B,T]
    const float* __restrict__ hin,   // [B,H]
    const float* __restrict__ Wih,   // [H]
    const float* __restrict__ Whh,   // [H,H]
    const float* __restrict__ bih,   // [H]
    const float* __restrict__ bhh,   // [H]
    const float* __restrict__ Wout,  // [H]
    const float* __restrict__ bout,  // [1]
    float* __restrict__ out,         // [B*T] ++ [B*H]
    int B)
{
    const int tid  = threadIdx.x;
    const int lane = tid & 63;
    const int l31  = lane & 31;
    const int hi   = lane >> 5;
    const int wave = tid >> 6;
    const int b0   = (blockIdx.x * 4 + wave) * 32 + l31;
    const int kb   = hi * 8;

    // ---- A fragments: Whh split hi/lo, both K-halves. Loaded ONCE. ----
    u32x4 A1h, A1l, A2h, A2l;
    load_split8(Whh + l31 * RNN_H + kb,      A1h, A1l);   // k = 0..15
    load_split8(Whh + l31 * RNN_H + 16 + kb, A2h, A2l);   // k = 16..31

    // ---- initial B fragments from h0 ----
    u32x4 B1h0, B1l0, B2h0, B2l0;
    load_split8(hin + (size_t)b0 * RNN_H + kb,      B1h0, B1l0);
    load_split8(hin + (size_t)b0 * RNN_H + 16 + kb, B2h0, B2l0);

    // ---- per-reg row constants: row(r) = (r&3) + 8*(r>>2) + 4*hi ----
    float wih_r[16], bias_r[16], wout_r[16];
    #pragma unroll
    for (int r = 0; r < 16; ++r) {
        int row = (r & 3) + 8 * (r >> 2) + 4 * hi;
        wih_r[r]  = Wih[row];
        bias_r[r] = bih[row] + bhh[row];
        wout_r[r] = Wout[row];
    }

    const float bo = bout[0];
    const float* xp0 = x + (size_t)b0 * RNN_T;
    float* op0 = out + (size_t)b0 * RNN_T;

    float h0r[16];
    float xc0 = xp0[0];

    #pragma unroll 1   // rolled, as in R5 (full unroll + permlane asm = R7 bug)
    for (int t = 0; t < RNN_T; ++t) {
        const int tn = (t < RNN_T - 1) ? t + 1 : t;   // branchless prefetch idx
        const float xn0 = xp0[tn];                    // hides under this body

        f32x16 acc0;
        #pragma unroll
        for (int r = 0; r < 16; ++r) acc0[r] = fmaf(xc0, wih_r[r], bias_r[r]);

        // 6 MFMAs (hi*hi, hi*lo, lo*hi; lo*lo dropped, ~2^-18)
        acc0 = mfma_bf16(A1h, B1h0, acc0);
        acc0 = mfma_bf16(A2h, B2h0, acc0);
        acc0 = mfma_bf16(A1h, B1l0, acc0);
        acc0 = mfma_bf16(A2h, B2l0, acc0);
        acc0 = mfma_bf16(A1l, B1h0, acc0);
        acc0 = mfma_bf16(A2l, B2h0, acc0);

        #pragma unroll
        for (int r = 0; r < 16; ++r) h0r[r] = fast_tanh(acc0[r]);

        // output head: o = sum_j h[j]*Wout[j]; partner holds the other 16 rows
        float o0 = 0.f;
        #pragma unroll
        for (int r = 0; r < 16; ++r) o0 = fmaf(h0r[r], wout_r[r], o0);
        unsigned oa0 = __float_as_uint(o0), ob0 = oa0;
        swap32(oa0, ob0);   // lo lanes: oa0 = own, ob0 = partner's
        if (lane < 32) {
            op0[t] = __uint_as_float(oa0) + __uint_as_float(ob0) + bo;
        }

        // rebuild next-step B fragments (done at t=9 too: ~1% waste, no branch)
        unsigned Sh[8], Sl[8];
        #pragma unroll
        for (int p = 0; p < 8; ++p) {
            float f0 = h0r[2 * p], f1 = h0r[2 * p + 1];
            Sh[p] = pack_hi_pair(f0, f1);
            Sl[p] = pack_hi_pair(f0 - trunc_bf16_f32(f0), f1 - trunc_bf16_f32(f1));
        }
        rebuild(Sh, B1h0, B2h0);
        rebuild(Sl, B1l0, B2l0);

        xc0 = xn0;
    }

    // ---- final hidden state: rows 8q+4*hi+0..3 are h[4q..4q+3] ----
    float* hl0 = out + (size_t)B * RNN_T + (size_t)b0 * RNN_H;
    #pragma unroll
    for (int q = 0; q < 4; ++q) {
        float4 v0 = make_float4(h0r[4*q], h0r[4*q+1], h0r[4*q+2], h0r[4*q+3]);
        *reinterpret_cast<float4*>(hl0 + 8 * q + 4 * hi) = v0;
    }
}

extern "C" void kernel_launch(void* const* d_in, const int* in_sizes, int n_in,
                              void* d_out, int out_size, void* d_ws, size_t ws_size,
                              hipStream_t stream) {
    const float* x    = (const float*)d_in[0];
    const float* h0   = (const float*)d_in[1];
    const float* Wih  = (const float*)d_in[2];
    const float* Whh  = (const float*)d_in[3];
    const float* bih  = (const float*)d_in[4];
    const float* bhh  = (const float*)d_in[5];
    const float* Wout = (const float*)d_in[6];
    const float* bout = (const float*)d_in[7];
    float* out = (float*)d_out;

    const int B = in_sizes[1] / RNN_H;     // 262144
    dim3 grid(B / 128);                    // 2048 blocks: 4 waves x 1 tile x 32
    dim3 block(256);
    hipLaunchKernelGGL(rnn_mfma5, grid, block, 0, stream,
                       x, h0, Wih, Whh, bih, bhh, Wout, bout, out, B);
}

// Round 11
// 139.766 us; speedup vs baseline: 1.0059x; 1.0025x over previous
//
#include <hip/hip_runtime.h>

// Elman RNN via split-bf16 MFMA, 2 tiles/wave at FULL grid spread.
// B=262144, T=10, I=1, H=32.  out = [outs (B*T)] ++ [h_last (B*H)]
//
// R10 post-mortem: R4/R5/R10 all ~55-58us despite ~30% issue-count changes
// -> latency/overlap-bound, not issue-bound. R5 (2 chains/wave) was
// confounded by half-grid; R10 (full grid) had 1 chain. This round: 2
// independent chains per wave AND 2048 blocks (block=128 = 2 waves).
// Body is R5's verbatim (passing) 2-tile code; only the block/tile
// mapping and grid change.
//
// Layouts (C/D guide-verified for 32x32x16 bf16; A/B verified R4/R5/R10):
//   C/D: col = lane&31, row = (reg&3) + 8*(reg>>2) + 4*(lane>>5)
//   A:   lane holds A[row=lane&31][k = (lane>>5)*8 + j], j=0..7
//   B:   lane holds B[k = (lane>>5)*8 + j][col=lane&31]
// permlane32_swap(X,Y): X'[i]=X[i], X'[32+i]=Y[i]; Y'[i]=X[32+i], Y'[32+i]=Y[32+i]

#define RNN_T 10
#define RNN_H 32

typedef __attribute__((ext_vector_type(4))) unsigned int u32x4;
typedef __attribute__((ext_vector_type(8))) short s16x8;
typedef __attribute__((ext_vector_type(16))) float f32x16;

static __device__ __forceinline__ float fast_tanh(float a) {
    // tanh(a) = 1 - 2/(exp(2a)+1); saturates correctly at +-inf.
    float ez = __builtin_amdgcn_exp2f(a * 2.885390081777927f);
    float r  = __builtin_amdgcn_rcpf(ez + 1.0f);
    return fmaf(-2.0f, r, 1.0f);
}

// pack bf16-trunc(f0) [low 16] and bf16-trunc(f1) [high 16] into one u32
static __device__ __forceinline__ unsigned pack_hi_pair(float f0, float f1) {
    return (__float_as_uint(f1) & 0xffff0000u) | (__float_as_uint(f0) >> 16);
}
static __device__ __forceinline__ float trunc_bf16_f32(float f) {
    return __uint_as_float(__float_as_uint(f) & 0xffff0000u);
}

static __device__ __forceinline__ f32x16 mfma_bf16(u32x4 a, u32x4 b, f32x16 c) {
    return __builtin_amdgcn_mfma_f32_32x32x16_bf16(
        __builtin_bit_cast(s16x8, a), __builtin_bit_cast(s16x8, b), c, 0, 0, 0);
}

// load 8 consecutive floats, split into bf16 hi fragment + bf16 residual fragment
static __device__ __forceinline__ void load_split8(const float* __restrict__ p,
                                                   u32x4& hi4, u32x4& lo4) {
    float4 w0 = *reinterpret_cast<const float4*>(p);
    float4 w1 = *reinterpret_cast<const float4*>(p + 4);
    float w[8] = {w0.x, w0.y, w0.z, w0.w, w1.x, w1.y, w1.z, w1.w};
    #pragma unroll
    for (int i = 0; i < 4; ++i) {
        float f0 = w[2 * i], f1 = w[2 * i + 1];
        hi4[i] = pack_hi_pair(f0, f1);
        lo4[i] = pack_hi_pair(f0 - trunc_bf16_f32(f0), f1 - trunc_bf16_f32(f1));
    }
}

static __device__ __forceinline__ void swap32(unsigned& xv, unsigned& yv) {
    asm volatile("v_permlane32_swap_b32 %0, %1" : "+v"(xv), "+v"(yv));
}

// S[p] = packed-bf16 pair (h[2p],h[2p+1]) in D-layout -> B-frag K-halves.
static __device__ __forceinline__ void rebuild(const unsigned S[8],
                                               u32x4& Bk1, u32x4& Bk2) {
    unsigned a, b;
    a = S[0]; b = S[2]; swap32(a, b); Bk1[0] = a; Bk1[2] = b;
    a = S[1]; b = S[3]; swap32(a, b); Bk1[1] = a; Bk1[3] = b;
    a = S[4]; b = S[6]; swap32(a, b); Bk2[0] = a; Bk2[2] = b;
    a = S[5]; b = S[7]; swap32(a, b); Bk2[1] = a; Bk2[3] = b;
}

__global__ __launch_bounds__(128) void rnn_mfma6(
    const float* __restrict__ x,     // [B,T]
    const float* __restrict__ hin,   // [B,H]
    const float* __restrict__ Wih,   // [H]
    const float* __restrict__ Whh,   // [H,H]
    const float* __restrict__ bih,   // [H]
    const float* __restrict__ bhh,   // [H]
    const float* __restrict__ Wout,  // [H]
    const float* __restrict__ bout,  // [1]
    float* __restrict__ out,         // [B*T] ++ [B*H]
    int B)
{
    const int tid  = threadIdx.x;
    const int lane = tid & 63;
    const int l31  = lane & 31;
    const int hi   = lane >> 5;
    const int wave = tid >> 6;                               // 0..1
    const int b0   = (blockIdx.x * 4 + wave * 2) * 32 + l31; // tile pair
    const int b1   = b0 + 32;
    const int kb   = hi * 8;

    // ---- A fragments: Whh split hi/lo, both K-halves. Loaded ONCE. ----
    u32x4 A1h, A1l, A2h, A2l;
    load_split8(Whh + l31 * RNN_H + kb,      A1h, A1l);   // k = 0..15
    load_split8(Whh + l31 * RNN_H + 16 + kb, A2h, A2l);   // k = 16..31

    // ---- initial B fragments from h0, two tiles ----
    u32x4 B1h0, B1l0, B2h0, B2l0, B1h1, B1l1, B2h1, B2l1;
    load_split8(hin + (size_t)b0 * RNN_H + kb,      B1h0, B1l0);
    load_split8(hin + (size_t)b0 * RNN_H + 16 + kb, B2h0, B2l0);
    load_split8(hin + (size_t)b1 * RNN_H + kb,      B1h1, B1l1);
    load_split8(hin + (size_t)b1 * RNN_H + 16 + kb, B2h1, B2l1);

    // ---- per-reg row constants: row(r) = (r&3) + 8*(r>>2) + 4*hi ----
    float wih_r[16], bias_r[16], wout_r[16];
    #pragma unroll
    for (int r = 0; r < 16; ++r) {
        int row = (r & 3) + 8 * (r >> 2) + 4 * hi;
        wih_r[r]  = Wih[row];
        bias_r[r] = bih[row] + bhh[row];
        wout_r[r] = Wout[row];
    }

    const float bo = bout[0];
    const float* xp0 = x + (size_t)b0 * RNN_T;
    const float* xp1 = x + (size_t)b1 * RNN_T;
    float* op0 = out + (size_t)b0 * RNN_T;
    float* op1 = out + (size_t)b1 * RNN_T;

    float h0r[16], h1r[16];
    float xc0 = xp0[0], xc1 = xp1[0];

    #pragma unroll 1   // rolled (R5-proven); full unroll + permlane asm = R7 bug
    for (int t = 0; t < RNN_T; ++t) {
        const int tn = (t < RNN_T - 1) ? t + 1 : t;   // branchless prefetch idx
        const float xn0 = xp0[tn], xn1 = xp1[tn];     // hides under this body

        f32x16 acc0, acc1;
        #pragma unroll
        for (int r = 0; r < 16; ++r) {
            acc0[r] = fmaf(xc0, wih_r[r], bias_r[r]);
            acc1[r] = fmaf(xc1, wih_r[r], bias_r[r]);
        }
        // 6 MFMAs/tile (hi*hi, hi*lo, lo*hi; lo*lo dropped, ~2^-18)
        acc0 = mfma_bf16(A1h, B1h0, acc0);  acc1 = mfma_bf16(A1h, B1h1, acc1);
        acc0 = mfma_bf16(A2h, B2h0, acc0);  acc1 = mfma_bf16(A2h, B2h1, acc1);
        acc0 = mfma_bf16(A1h, B1l0, acc0);  acc1 = mfma_bf16(A1h, B1l1, acc1);
        acc0 = mfma_bf16(A2h, B2l0, acc0);  acc1 = mfma_bf16(A2h, B2l1, acc1);
        acc0 = mfma_bf16(A1l, B1h0, acc0);  acc1 = mfma_bf16(A1l, B1h1, acc1);
        acc0 = mfma_bf16(A2l, B2h0, acc0);  acc1 = mfma_bf16(A2l, B2h1, acc1);

        #pragma unroll
        for (int r = 0; r < 16; ++r) {
            h0r[r] = fast_tanh(acc0[r]);
            h1r[r] = fast_tanh(acc1[r]);
        }

        // output head: o = sum_j h[j]*Wout[j]; partner holds the other 16 rows
        float o0 = 0.f, o1 = 0.f;
        #pragma unroll
        for (int r = 0; r < 16; ++r) {
            o0 = fmaf(h0r[r], wout_r[r], o0);
            o1 = fmaf(h1r[r], wout_r[r], o1);
        }
        unsigned oa0 = __float_as_uint(o0), ob0 = oa0;
        unsigned oa1 = __float_as_uint(o1), ob1 = oa1;
        swap32(oa0, ob0);   // lo lanes: oa = own, ob = partner's
        swap32(oa1, ob1);
        if (lane < 32) {
            op0[t] = __uint_as_float(oa0) + __uint_as_float(ob0) + bo;
            op1[t] = __uint_as_float(oa1) + __uint_as_float(ob1) + bo;
        }

        // rebuild next-step B fragments (done at t=9 too: ~1% waste, no branch)
        unsigned Sh[8], Sl[8];
        #pragma unroll
        for (int p = 0; p < 8; ++p) {
            float f0 = h0r[2 * p], f1 = h0r[2 * p + 1];
            Sh[p] = pack_hi_pair(f0, f1);
            Sl[p] = pack_hi_pair(f0 - trunc_bf16_f32(f0), f1 - trunc_bf16_f32(f1));
        }
        rebuild(Sh, B1h0, B2h0);
        rebuild(Sl, B1l0, B2l0);
        #pragma unroll
        for (int p = 0; p < 8; ++p) {
            float f0 = h1r[2 * p], f1 = h1r[2 * p + 1];
            Sh[p] = pack_hi_pair(f0, f1);
            Sl[p] = pack_hi_pair(f0 - trunc_bf16_f32(f0), f1 - trunc_bf16_f32(f1));
        }
        rebuild(Sh, B1h1, B2h1);
        rebuild(Sl, B1l1, B2l1);

        xc0 = xn0; xc1 = xn1;
    }

    // ---- final hidden state: rows 8q+4*hi+0..3 are h[4q..4q+3] ----
    float* hl0 = out + (size_t)B * RNN_T + (size_t)b0 * RNN_H;
    float* hl1 = out + (size_t)B * RNN_T + (size_t)b1 * RNN_H;
    #pragma unroll
    for (int q = 0; q < 4; ++q) {
        float4 v0 = make_float4(h0r[4*q], h0r[4*q+1], h0r[4*q+2], h0r[4*q+3]);
        float4 v1 = make_float4(h1r[4*q], h1r[4*q+1], h1r[4*q+2], h1r[4*q+3]);
        *reinterpret_cast<float4*>(hl0 + 8 * q + 4 * hi) = v0;
        *reinterpret_cast<float4*>(hl1 + 8 * q + 4 * hi) = v1;
    }
}

extern "C" void kernel_launch(void* const* d_in, const int* in_sizes, int n_in,
                              void* d_out, int out_size, void* d_ws, size_t ws_size,
                              hipStream_t stream) {
    const float* x    = (const float*)d_in[0];
    const float* h0   = (const float*)d_in[1];
    const float* Wih  = (const float*)d_in[2];
    const float* Whh  = (const float*)d_in[3];
    const float* bih  = (const float*)d_in[4];
    const float* bhh  = (const float*)d_in[5];
    const float* Wout = (const float*)d_in[6];
    const float* bout = (const float*)d_in[7];
    float* out = (float*)d_out;

    const int B = in_sizes[1] / RNN_H;     // 262144
    dim3 grid(B / 128);                    // 2048 blocks: 2 waves x 2 tiles x 32
    dim3 block(128);
    hipLaunchKernelGGL(rnn_mfma6, grid, block, 0, stream,
                       x, h0, Wih, Whh, bih, bhh, Wout, bout, out, B);
}